// Round 4
// baseline (641.935 us; speedup 1.0000x reference)
//
#include <hip/hip_runtime.h>
#include <hip/hip_bf16.h>

#define T_TOK 2048
#define D_DIM 2048
#define N_EXP 8
#define F_DIM 1024

typedef __attribute__((ext_vector_type(8))) short short8;
typedef __attribute__((ext_vector_type(4))) float floatx4;

// s_waitcnt imm: vmcnt[3:0]|simm[15:14], expcnt=7 (bits 6:4), lgkmcnt=15 (bits 11:8)
#define WAIT_VM12 0xF7C   // vmcnt <= 12, lgkm/exp ignored
#define WAIT_VM0  0xF70   // vmcnt <= 0

__device__ __forceinline__ short f2bf(float f) {
  union { float f; unsigned u; } v; v.f = f;
  unsigned r = v.u + 0x7fffu + ((v.u >> 16) & 1u);
  return (short)(r >> 16);
}

__device__ __forceinline__ floatx4 mfma16(short8 a, short8 b, floatx4 c) {
  return __builtin_amdgcn_mfma_f32_16x16x32_bf16(a, b, c, 0, 0, 0);
}

__device__ __forceinline__ void gload16(const void* g, void* l) {
  __builtin_amdgcn_global_load_lds(
      (const __attribute__((address_space(1))) unsigned int*)g,
      (__attribute__((address_space(3))) unsigned int*)l, 16, 0, 0);
}

// ---------------- transpose + fp32->bf16 convert: dst[c][r] = src[r][c] per expert ----
__global__ __launch_bounds__(256) void transpose_cvt(const float* __restrict__ src,
                                                     short* __restrict__ dst,
                                                     int R, int C) {
  __shared__ float tile[32][33];
  int e = blockIdx.z;
  src += (size_t)e * R * C;
  dst += (size_t)e * R * C;
  int c0 = blockIdx.x * 32, r0 = blockIdx.y * 32;
  int tx = threadIdx.x & 31, ty = threadIdx.x >> 5;
#pragma unroll
  for (int i = 0; i < 32; i += 8)
    tile[ty + i][tx] = src[(size_t)(r0 + ty + i) * C + c0 + tx];
  __syncthreads();
#pragma unroll
  for (int i = 0; i < 32; i += 8)
    dst[(size_t)(c0 + ty + i) * R + r0 + tx] = f2bf(tile[tx][ty + i]);
}

// ---------------- router: logits (fp32), top-2, expert lists, x -> bf16 --------------
__global__ __launch_bounds__(256) void router_kernel(
    const float* __restrict__ x, const float* __restrict__ gate_w,
    short* __restrict__ x_bf, float* __restrict__ out_logits,
    int* __restrict__ counts, int* __restrict__ tok_ids, float* __restrict__ tok_wts) {
  int t = blockIdx.x;
  int tid = threadIdx.x;
  const float* xr = x + (size_t)t * D_DIM + tid * 8;
  floatx4 xv0 = *(const floatx4*)xr;
  floatx4 xv1 = *(const floatx4*)(xr + 4);
  float xs[8];
#pragma unroll
  for (int j = 0; j < 4; j++) { xs[j] = xv0[j]; xs[4 + j] = xv1[j]; }
  union { short8 v; short s[8]; } xb;
#pragma unroll
  for (int j = 0; j < 8; j++) xb.s[j] = f2bf(xs[j]);
  *(short8*)(x_bf + (size_t)t * D_DIM + tid * 8) = xb.v;

  float p[N_EXP];
#pragma unroll
  for (int e = 0; e < N_EXP; e++) {
    const float* gw = gate_w + (size_t)e * D_DIM + tid * 8;
    floatx4 g0 = *(const floatx4*)gw;
    floatx4 g1 = *(const floatx4*)(gw + 4);
    float s = 0.f;
#pragma unroll
    for (int j = 0; j < 4; j++) s += xs[j] * g0[j] + xs[4 + j] * g1[j];
    p[e] = s;
  }
  __shared__ float red[N_EXP * 4];
  __shared__ float slog[N_EXP];
  int lane = tid & 63, wv = tid >> 6;
#pragma unroll
  for (int e = 0; e < N_EXP; e++) {
    float v = p[e];
#pragma unroll
    for (int off = 32; off > 0; off >>= 1) v += __shfl_down(v, off);
    if (lane == 0) red[e * 4 + wv] = v;
  }
  __syncthreads();
  if (tid < N_EXP) {
    float s = red[tid * 4] + red[tid * 4 + 1] + red[tid * 4 + 2] + red[tid * 4 + 3];
    slog[tid] = s;
    out_logits[(size_t)t * N_EXP + tid] = s;
  }
  __syncthreads();
  if (tid == 0) {
    float l[N_EXP];
#pragma unroll
    for (int e = 0; e < N_EXP; e++) l[e] = slog[e];
    int e0 = 0;
#pragma unroll
    for (int e = 1; e < N_EXP; e++) if (l[e] > l[e0]) e0 = e;
    int e1 = (e0 == 0) ? 1 : 0;
#pragma unroll
    for (int e = 0; e < N_EXP; e++) if (e != e0 && l[e] > l[e1]) e1 = e;
    float p1 = __expf(l[e1] - l[e0]);
    float s = 1.f + p1;
    int pos0 = atomicAdd(&counts[e0], 1);
    tok_ids[e0 * T_TOK + pos0] = t;             // k = 0
    tok_wts[e0 * T_TOK + pos0] = 1.f / s;
    int pos1 = atomicAdd(&counts[e1], 1);
    tok_ids[e1 * T_TOK + pos1] = t | (1 << 16); // k = 1
    tok_wts[e1 * T_TOK + pos1] = p1 / s;
  }
}

// ---------------- GEMM1: 128x128, BK=64, triple-buffer dist-2 manual pipeline --------
// grid is ~1 block/CU, so latency must be hidden INTRA-block: prefetch distance 2,
// wait vmcnt<=12 (leave next step's 12 loads in flight), raw s_barrier.
__global__ __launch_bounds__(256, 2) void gemm1_kernel(
    const short* __restrict__ x_bf,
    const short* __restrict__ wgT, const short* __restrict__ wuT,
    const int* __restrict__ counts, const int* __restrict__ tok_ids,
    const float* __restrict__ tok_wts,
    short* __restrict__ hbuf) {
  int e = blockIdx.x >> 4;
  int mt = blockIdx.x & 15;
  int count = counts[e];
  if (mt * 128 >= count) return;
  int f0 = blockIdx.y * 128;

  __shared__ short sA[3][8192];
  __shared__ short sBg[3][8192];
  __shared__ short sBu[3][8192];
  __shared__ int s_tok[128];
  __shared__ float s_wt[128];

  int tid = threadIdx.x;
  if (tid < 128) {
    int r = mt * 128 + tid;
    if (r < count) { s_tok[tid] = tok_ids[e * T_TOK + r]; s_wt[tid] = tok_wts[e * T_TOK + r]; }
    else { s_tok[tid] = 0; s_wt[tid] = 0.f; }
  }
  __syncthreads();

  int lane = tid & 63, wv = tid >> 6;
  int wr = wv >> 1, wc = wv & 1;
  int l16 = lane & 15, qd = lane >> 4;
  int lr = lane >> 3, lc = lane & 7;
  int csw8 = (lc ^ lr) * 8;   // XOR swizzle: global chunk this lane stages

  int offA[4], offB[4];
#pragma unroll
  for (int it = 0; it < 4; it++) {
    int r = wv * 32 + it * 8 + lr;                    // 8 rows per wave per it
    offA[it] = (s_tok[r] & 0xFFFF) * D_DIM + csw8;
    offB[it] = (e * F_DIM + f0 + r) * D_DIM + csw8;   // same offset for wg and wu
  }

  floatx4 accG[4][4] = {};
  floatx4 accU[4][4] = {};
  int sw = l16 & 7;

  auto issueStep = [&](int s, int b) {
    int d0 = s * 64;
#pragma unroll
    for (int it = 0; it < 4; it++) {
      gload16(x_bf + offA[it] + d0, &sA[b][wv * 2048 + it * 512]);
      gload16(wgT  + offB[it] + d0, &sBg[b][wv * 2048 + it * 512]);
      gload16(wuT  + offB[it] + d0, &sBu[b][wv * 2048 + it * 512]);
    }
  };
  auto computeStep = [&](int b) {
    const short* rA  = &sA[b][(wr * 64 + l16) * 64];
    const short* rBg = &sBg[b][(wc * 64 + l16) * 64];
    const short* rBu = &sBu[b][(wc * 64 + l16) * 64];
#pragma unroll
    for (int kk = 0; kk < 2; kk++) {
      short8 a[4], bg[4], bu[4];
      int c = ((kk * 4 + qd) ^ sw) * 8;
#pragma unroll
      for (int mi = 0; mi < 4; mi++) a[mi] = *(const short8*)(rA + mi * 16 * 64 + c);
#pragma unroll
      for (int nj = 0; nj < 4; nj++) {
        bg[nj] = *(const short8*)(rBg + nj * 16 * 64 + c);
        bu[nj] = *(const short8*)(rBu + nj * 16 * 64 + c);
      }
#pragma unroll
      for (int mi = 0; mi < 4; mi++)
#pragma unroll
        for (int nj = 0; nj < 4; nj++) {
          accG[mi][nj] = mfma16(a[mi], bg[nj], accG[mi][nj]);
          accU[mi][nj] = mfma16(a[mi], bu[nj], accU[mi][nj]);
        }
    }
  };

  const int NS = D_DIM / 64;   // 32
  issueStep(0, 0);
  issueStep(1, 1);
  for (int s = 0; s < NS; s++) {
    if (s + 1 < NS) __builtin_amdgcn_s_waitcnt(WAIT_VM12);  // step s done, s+1 in flight
    else            __builtin_amdgcn_s_waitcnt(WAIT_VM0);   // last step: drain all
    __builtin_amdgcn_s_barrier();
    if (s + 2 < NS) issueStep(s + 2, (s + 2) % 3);
    computeStep(s % 3);
  }

#pragma unroll
  for (int mi = 0; mi < 4; mi++)
#pragma unroll
    for (int r = 0; r < 4; r++) {
      int rowl = wr * 64 + mi * 16 + qd * 4 + r;
      if (mt * 128 + rowl < count) {
        int raw = s_tok[rowl];
        int hrow = (raw & 0xFFFF) * 2 + (raw >> 16);
        float wt = s_wt[rowl];
        short* hdst = hbuf + (size_t)hrow * F_DIM + f0 + wc * 64 + l16;
#pragma unroll
        for (int nj = 0; nj < 4; nj++) {
          float g = accG[mi][nj][r], u = accU[mi][nj][r];
          float sg = g / (1.f + __expf(-g));
          hdst[nj * 16] = f2bf(sg * u * wt);
        }
      }
    }
}

// ---------------- GEMM2: 128x128, BK=64, double-buffer (2 blocks/CU) -----------------
__global__ __launch_bounds__(256, 2) void gemm2_kernel(
    const short* __restrict__ hbuf, const short* __restrict__ wdT,
    const int* __restrict__ counts, const int* __restrict__ tok_ids,
    float* __restrict__ outY) {
  int e = blockIdx.x >> 4;
  int mt = blockIdx.x & 15;
  int count = counts[e];
  if (mt * 128 >= count) return;
  int n0 = blockIdx.y * 128;

  __shared__ short sA[2][8192];
  __shared__ short sB[2][8192];
  __shared__ int s_tok[128];

  int tid = threadIdx.x;
  if (tid < 128) {
    int r = mt * 128 + tid;
    s_tok[tid] = (r < count) ? tok_ids[e * T_TOK + r] : 0;
  }
  __syncthreads();

  int lane = tid & 63, wv = tid >> 6;
  int wr = wv >> 1, wc = wv & 1;
  int l16 = lane & 15, qd = lane >> 4;
  int lr = lane >> 3, lc = lane & 7;
  int csw8 = (lc ^ lr) * 8;

  int offA[4], offB[4];
#pragma unroll
  for (int it = 0; it < 4; it++) {
    int r = wv * 32 + it * 8 + lr;                    // 8 rows per wave per it
    int raw = s_tok[r];
    offA[it] = ((raw & 0xFFFF) * 2 + (raw >> 16)) * F_DIM + csw8;
    offB[it] = (e * D_DIM + n0 + r) * F_DIM + csw8;
  }

  floatx4 acc[4][4] = {};
  int sw = l16 & 7;

  auto issueStep = [&](int s, int b) {
    int k0 = s * 64;
#pragma unroll
    for (int it = 0; it < 4; it++) {
      gload16(hbuf + offA[it] + k0, &sA[b][wv * 2048 + it * 512]);
      gload16(wdT  + offB[it] + k0, &sB[b][wv * 2048 + it * 512]);
    }
  };

  const int NS = F_DIM / 64;   // 16
  issueStep(0, 0);
  for (int s = 0; s < NS; s++) {
    __syncthreads();           // drains step-s loads (issued one compute phase ago)
    if (s + 1 < NS) issueStep(s + 1, (s + 1) & 1);
    const short* rA = &sA[s & 1][(wr * 64 + l16) * 64];
    const short* rB = &sB[s & 1][(wc * 64 + l16) * 64];
#pragma unroll
    for (int kk = 0; kk < 2; kk++) {
      short8 a[4], b[4];
      int c = ((kk * 4 + qd) ^ sw) * 8;
#pragma unroll
      for (int mi = 0; mi < 4; mi++) a[mi] = *(const short8*)(rA + mi * 16 * 64 + c);
#pragma unroll
      for (int nj = 0; nj < 4; nj++) b[nj] = *(const short8*)(rB + nj * 16 * 64 + c);
#pragma unroll
      for (int mi = 0; mi < 4; mi++)
#pragma unroll
        for (int nj = 0; nj < 4; nj++)
          acc[mi][nj] = mfma16(a[mi], b[nj], acc[mi][nj]);
    }
  }

#pragma unroll
  for (int mi = 0; mi < 4; mi++)
#pragma unroll
    for (int r = 0; r < 4; r++) {
      int rowl = wr * 64 + mi * 16 + qd * 4 + r;
      if (mt * 128 + rowl < count) {
        int tok = s_tok[rowl] & 0xFFFF;
        float* dst = outY + (size_t)tok * D_DIM + n0 + wc * 64 + l16;
#pragma unroll
        for (int nj = 0; nj < 4; nj++)
          unsafeAtomicAdd(&dst[nj * 16], acc[mi][nj][r]);
      }
    }
}

extern "C" void kernel_launch(void* const* d_in, const int* in_sizes, int n_in,
                              void* d_out, int out_size, void* d_ws, size_t ws_size,
                              hipStream_t stream) {
  (void)in_sizes; (void)n_in; (void)out_size; (void)ws_size;
  const float* hidden = (const float*)d_in[0];
  const float* gate_w = (const float*)d_in[1];
  const float* w_gate = (const float*)d_in[2];
  const float* w_up   = (const float*)d_in[3];
  const float* w_down = (const float*)d_in[4];
  float* out = (float*)d_out;
  float* outY = out;                                   // [T, D]
  float* outLogits = out + (size_t)T_TOK * D_DIM;      // [T, E]

  char* ws = (char*)d_ws;
  size_t off = 0;
  int* counts = (int*)(ws + off); off += 256;
  int* tok_ids = (int*)(ws + off); off += (size_t)N_EXP * T_TOK * 4;
  float* tok_wts = (float*)(ws + off); off += (size_t)N_EXP * T_TOK * 4;
  short* x_bf = (short*)(ws + off); off += (size_t)T_TOK * D_DIM * 2;
  short* wgT = (short*)(ws + off); off += (size_t)N_EXP * F_DIM * D_DIM * 2;
  short* wuT = (short*)(ws + off); off += (size_t)N_EXP * F_DIM * D_DIM * 2;
  short* wdT = (short*)(ws + off); off += (size_t)N_EXP * D_DIM * F_DIM * 2;
  short* hbuf = (short*)(ws + off); off += (size_t)T_TOK * 2 * F_DIM * 2;

  hipMemsetAsync(counts, 0, 256, stream);
  hipMemsetAsync(outY, 0, (size_t)T_TOK * D_DIM * 4, stream);

  // weights: [E][D][F] -> [E][F][D] (wg, wu), [E][F][D] -> [E][D][F] (wd)
  transpose_cvt<<<dim3(F_DIM / 32, D_DIM / 32, N_EXP), 256, 0, stream>>>(w_gate, wgT, D_DIM, F_DIM);
  transpose_cvt<<<dim3(F_DIM / 32, D_DIM / 32, N_EXP), 256, 0, stream>>>(w_up,   wuT, D_DIM, F_DIM);
  transpose_cvt<<<dim3(D_DIM / 32, F_DIM / 32, N_EXP), 256, 0, stream>>>(w_down, wdT, F_DIM, D_DIM);

  router_kernel<<<T_TOK, 256, 0, stream>>>(hidden, gate_w, x_bf, outLogits,
                                           counts, tok_ids, tok_wts);

  gemm1_kernel<<<dim3(N_EXP * 16, F_DIM / 128), 256, 0, stream>>>(
      x_bf, wgT, wuT, counts, tok_ids, tok_wts, hbuf);

  gemm2_kernel<<<dim3(N_EXP * 16, D_DIM / 128), 256, 0, stream>>>(
      hbuf, wdT, counts, tok_ids, outY);
}

// Round 5
// 480.403 us; speedup vs baseline: 1.3362x; 1.3362x over previous
//
#include <hip/hip_runtime.h>
#include <hip/hip_bf16.h>

#define T_TOK 2048
#define D_DIM 2048
#define N_EXP 8
#define F_DIM 1024

typedef __attribute__((ext_vector_type(8))) short short8;
typedef __attribute__((ext_vector_type(4))) float floatx4;

__device__ __forceinline__ short f2bf(float f) {
  union { float f; unsigned u; } v; v.f = f;
  unsigned r = v.u + 0x7fffu + ((v.u >> 16) & 1u);
  return (short)(r >> 16);
}

__device__ __forceinline__ floatx4 mfma16(short8 a, short8 b, floatx4 c) {
  return __builtin_amdgcn_mfma_f32_16x16x32_bf16(a, b, c, 0, 0, 0);
}

__device__ __forceinline__ void gload16(const void* g, void* l) {
  __builtin_amdgcn_global_load_lds(
      (const __attribute__((address_space(1))) unsigned int*)g,
      (__attribute__((address_space(3))) unsigned int*)l, 16, 0, 0);
}

// ---- transpose+cvt+PACK wg/wu: [E][D][F] -> pw[((e*16+fb)*32+s)*4096 + r*64 + c]
// (fb = f>>6, r = f&63, s = d>>6, c = d&63) : each (fb,s) chunk is 8KB contiguous.
__global__ __launch_bounds__(256) void pack_wgwu(const float* __restrict__ src,
                                                 short* __restrict__ dst) {
  int fb = blockIdx.x, s = blockIdx.y, e = blockIdx.z;
  __shared__ float tile[64][65];   // [d-local][f-local]
  int tx = threadIdx.x & 63, ty = threadIdx.x >> 6;
  const float* sp = src + (size_t)e * D_DIM * F_DIM + (size_t)(s * 64) * F_DIM + fb * 64;
#pragma unroll
  for (int i = 0; i < 64; i += 4)
    tile[ty + i][tx] = sp[(size_t)(ty + i) * F_DIM + tx];
  __syncthreads();
  short* dp = dst + (size_t)((e * 16 + fb) * 32 + s) * 4096;
#pragma unroll
  for (int i = 0; i < 64; i += 4)
    dp[(ty + i) * 64 + tx] = f2bf(tile[tx][ty + i]);   // dst[r][c] = src(d=s64+c, f=fb64+r)
}

// ---- transpose+cvt+PACK wd: [E][F][D] -> pw[((e*16+nb)*16+s)*8192 + r*64 + c]
// (nb = d>>7, r = d&127, s = f>>6, c = f&63) : each (nb,s) chunk is 16KB contiguous.
__global__ __launch_bounds__(256) void pack_wd(const float* __restrict__ src,
                                               short* __restrict__ dst) {
  int nb = blockIdx.x, s = blockIdx.y, e = blockIdx.z;
  __shared__ float tile[64][129];  // [k-local][n-local]
  int tx2 = threadIdx.x & 127, ty2 = threadIdx.x >> 7;
  const float* sp = src + (size_t)e * F_DIM * D_DIM + (size_t)(s * 64) * D_DIM + nb * 128;
#pragma unroll
  for (int i = 0; i < 64; i += 2)
    tile[ty2 + i][tx2] = sp[(size_t)(ty2 + i) * D_DIM + tx2];
  __syncthreads();
  int tx = threadIdx.x & 63, ty = threadIdx.x >> 6;
  short* dp = dst + (size_t)((e * 16 + nb) * 16 + s) * 8192;
#pragma unroll
  for (int r = 0; r < 128; r += 4)
    dp[(r + ty) * 64 + tx] = f2bf(tile[tx][r + ty]);   // dst[r][c] = src(f=s64+c, d=nb128+r)
}

// ---------------- router: logits (fp32), top-2, expert lists, x -> bf16 --------------
__global__ __launch_bounds__(256) void router_kernel(
    const float* __restrict__ x, const float* __restrict__ gate_w,
    short* __restrict__ x_bf, float* __restrict__ out_logits,
    int* __restrict__ counts, int* __restrict__ tok_ids, float* __restrict__ tok_wts) {
  int t = blockIdx.x;
  int tid = threadIdx.x;
  const float* xr = x + (size_t)t * D_DIM + tid * 8;
  floatx4 xv0 = *(const floatx4*)xr;
  floatx4 xv1 = *(const floatx4*)(xr + 4);
  float xs[8];
#pragma unroll
  for (int j = 0; j < 4; j++) { xs[j] = xv0[j]; xs[4 + j] = xv1[j]; }
  union { short8 v; short s[8]; } xb;
#pragma unroll
  for (int j = 0; j < 8; j++) xb.s[j] = f2bf(xs[j]);
  *(short8*)(x_bf + (size_t)t * D_DIM + tid * 8) = xb.v;

  float p[N_EXP];
#pragma unroll
  for (int e = 0; e < N_EXP; e++) {
    const float* gw = gate_w + (size_t)e * D_DIM + tid * 8;
    floatx4 g0 = *(const floatx4*)gw;
    floatx4 g1 = *(const floatx4*)(gw + 4);
    float s = 0.f;
#pragma unroll
    for (int j = 0; j < 4; j++) s += xs[j] * g0[j] + xs[4 + j] * g1[j];
    p[e] = s;
  }
  __shared__ float red[N_EXP * 4];
  __shared__ float slog[N_EXP];
  int lane = tid & 63, wv = tid >> 6;
#pragma unroll
  for (int e = 0; e < N_EXP; e++) {
    float v = p[e];
#pragma unroll
    for (int off = 32; off > 0; off >>= 1) v += __shfl_down(v, off);
    if (lane == 0) red[e * 4 + wv] = v;
  }
  __syncthreads();
  if (tid < N_EXP) {
    float s = red[tid * 4] + red[tid * 4 + 1] + red[tid * 4 + 2] + red[tid * 4 + 3];
    slog[tid] = s;
    out_logits[(size_t)t * N_EXP + tid] = s;
  }
  __syncthreads();
  if (tid == 0) {
    float l[N_EXP];
#pragma unroll
    for (int e = 0; e < N_EXP; e++) l[e] = slog[e];
    int e0 = 0;
#pragma unroll
    for (int e = 1; e < N_EXP; e++) if (l[e] > l[e0]) e0 = e;
    int e1 = (e0 == 0) ? 1 : 0;
#pragma unroll
    for (int e = 0; e < N_EXP; e++) if (e != e0 && l[e] > l[e1]) e1 = e;
    float p1 = __expf(l[e1] - l[e0]);
    float s = 1.f + p1;
    int pos0 = atomicAdd(&counts[e0], 1);
    tok_ids[e0 * T_TOK + pos0] = t;             // k = 0
    tok_wts[e0 * T_TOK + pos0] = 1.f / s;
    int pos1 = atomicAdd(&counts[e1], 1);
    tok_ids[e1 * T_TOK + pos1] = t | (1 << 16); // k = 1
    tok_wts[e1 * T_TOK + pos1] = p1 / s;
  }
}

// ---------------- tok2row: inverse map (token,k) -> sorted h row ---------------------
__global__ __launch_bounds__(256) void tok2row_kernel(
    const int* __restrict__ counts, const int* __restrict__ tok_ids,
    int* __restrict__ tok2row) {
  int tid = threadIdx.x;
  int base = 0;
  for (int e = 0; e < N_EXP; e++) {
    int c = counts[e];
    for (int pos = tid; pos < c; pos += 256) {
      int raw = tok_ids[e * T_TOK + pos];
      tok2row[(raw & 0xFFFF) * 2 + (raw >> 16)] = base + pos;
    }
    base += c;
  }
}

// ---------------- GEMM1: 128M x 64N, BK=64, packed-B streaming -----------------------
// h_sorted[hb + mt*128 + row][f] = silu(x Wg) * (x Wu) * route_w
__global__ __launch_bounds__(256, 2) void gemm1_kernel(
    const short* __restrict__ x_bf,
    const short* __restrict__ pwg, const short* __restrict__ pwu,
    const int* __restrict__ counts, const int* __restrict__ tok_ids,
    const float* __restrict__ tok_wts,
    short* __restrict__ h_sorted) {
  int e = blockIdx.x >> 4;
  int mt = blockIdx.x & 15;
  int count = counts[e];
  if (mt * 128 >= count) return;
  int fb = blockIdx.y;
  int hb = 0;
#pragma unroll
  for (int i = 0; i < N_EXP; i++) { int c = counts[i]; if (i < e) hb += c; }

  __shared__ short sA[8192];    // 128 x 64
  __shared__ short sBg[4096];   // 64 x 64
  __shared__ short sBu[4096];
  __shared__ int s_tok[128];
  __shared__ float s_wt[128];

  int tid = threadIdx.x;
  if (tid < 128) {
    int r = mt * 128 + tid;
    if (r < count) { s_tok[tid] = tok_ids[e * T_TOK + r]; s_wt[tid] = tok_wts[e * T_TOK + r]; }
    else { s_tok[tid] = 0; s_wt[tid] = 0.f; }
  }
  __syncthreads();

  int lane = tid & 63, wv = tid >> 6;
  int wr = wv >> 1, wc = wv & 1;
  int l16 = lane & 15, qd = lane >> 4;
  int lr = lane >> 3, lc = lane & 7;
  int csw8 = (lc ^ lr) * 8;   // XOR swizzle: LDS[row][pos] holds chunk pos^(row&7)

  int offA[4], offB[2];
#pragma unroll
  for (int it = 0; it < 4; it++) {
    int r = wv * 32 + it * 8 + lr;
    offA[it] = (s_tok[r] & 0xFFFF) * D_DIM + csw8;
  }
#pragma unroll
  for (int it = 0; it < 2; it++)
    offB[it] = (wv * 16 + it * 8 + lr) * 64 + csw8;   // within packed 8KB chunk
  const short* pBg = pwg + (size_t)((e * 16 + fb) * 32) * 4096;
  const short* pBu = pwu + (size_t)((e * 16 + fb) * 32) * 4096;

  floatx4 accG[4][2] = {};
  floatx4 accU[4][2] = {};
  int sw = l16 & 7;
  const short* rA  = sA  + (wr * 64 + l16) * 64;
  const short* rBg = sBg + (wc * 32 + l16) * 64;
  const short* rBu = sBu + (wc * 32 + l16) * 64;

  for (int s = 0; s < D_DIM / 64; s++) {
    __syncthreads();
#pragma unroll
    for (int it = 0; it < 4; it++)
      gload16(x_bf + offA[it] + s * 64, sA + wv * 2048 + it * 512);
#pragma unroll
    for (int it = 0; it < 2; it++) {
      gload16(pBg + (size_t)s * 4096 + offB[it], sBg + wv * 1024 + it * 512);
      gload16(pBu + (size_t)s * 4096 + offB[it], sBu + wv * 1024 + it * 512);
    }
    __syncthreads();
#pragma unroll
    for (int kk = 0; kk < 2; kk++) {
      short8 a[4], bg[2], bu[2];
      int c = ((kk * 4 + qd) ^ sw) * 8;
#pragma unroll
      for (int mi = 0; mi < 4; mi++) a[mi] = *(const short8*)(rA + mi * 16 * 64 + c);
#pragma unroll
      for (int nj = 0; nj < 2; nj++) {
        bg[nj] = *(const short8*)(rBg + nj * 16 * 64 + c);
        bu[nj] = *(const short8*)(rBu + nj * 16 * 64 + c);
      }
#pragma unroll
      for (int mi = 0; mi < 4; mi++)
#pragma unroll
        for (int nj = 0; nj < 2; nj++) {
          accG[mi][nj] = mfma16(a[mi], bg[nj], accG[mi][nj]);
          accU[mi][nj] = mfma16(a[mi], bu[nj], accU[mi][nj]);
        }
    }
  }

#pragma unroll
  for (int mi = 0; mi < 4; mi++)
#pragma unroll
    for (int r = 0; r < 4; r++) {
      int rowl = wr * 64 + mi * 16 + qd * 4 + r;
      if (mt * 128 + rowl < count) {
        float wt = s_wt[rowl];
        short* hdst = h_sorted + (size_t)(hb + mt * 128 + rowl) * F_DIM
                    + fb * 64 + wc * 32 + l16;
#pragma unroll
        for (int nj = 0; nj < 2; nj++) {
          float g = accG[mi][nj][r], u = accU[mi][nj][r];
          float sg = g / (1.f + __expf(-g));
          hdst[nj * 16] = f2bf(sg * u * wt);
        }
      }
    }
}

// ---------------- GEMM2: 128x128, BK=64, packed-B + sorted-A, plain stores -----------
__global__ __launch_bounds__(256, 2) void gemm2_kernel(
    const short* __restrict__ h_sorted, const short* __restrict__ pwd,
    const int* __restrict__ counts,
    float* __restrict__ y_sorted) {
  int e = blockIdx.x >> 4;
  int mt = blockIdx.x & 15;
  int count = counts[e];
  if (mt * 128 >= count) return;
  int nb = blockIdx.y;
  int hb = 0;
#pragma unroll
  for (int i = 0; i < N_EXP; i++) { int c = counts[i]; if (i < e) hb += c; }

  __shared__ short sA[8192];
  __shared__ short sB[8192];

  int tid = threadIdx.x;
  int lane = tid & 63, wv = tid >> 6;
  int wr = wv >> 1, wc = wv & 1;
  int l16 = lane & 15, qd = lane >> 4;
  int lr = lane >> 3, lc = lane & 7;
  int csw8 = (lc ^ lr) * 8;

  int offA[4], offB[4];
#pragma unroll
  for (int it = 0; it < 4; it++) {
    int r = wv * 32 + it * 8 + lr;
    offA[it] = (hb + mt * 128 + r) * F_DIM + csw8;     // contiguous sorted rows
    offB[it] = r * 64 + csw8;                          // within packed 16KB chunk
  }
  const short* pB = pwd + (size_t)((e * 16 + nb) * 16) * 8192;

  floatx4 acc[4][4] = {};
  int sw = l16 & 7;
  const short* rA = sA + (wr * 64 + l16) * 64;
  const short* rB = sB + (wc * 64 + l16) * 64;

  for (int s = 0; s < F_DIM / 64; s++) {
    __syncthreads();
#pragma unroll
    for (int it = 0; it < 4; it++) {
      gload16(h_sorted + offA[it] + s * 64, sA + wv * 2048 + it * 512);
      gload16(pB + (size_t)s * 8192 + offB[it], sB + wv * 2048 + it * 512);
    }
    __syncthreads();
#pragma unroll
    for (int kk = 0; kk < 2; kk++) {
      short8 a[4], b[4];
      int c = ((kk * 4 + qd) ^ sw) * 8;
#pragma unroll
      for (int mi = 0; mi < 4; mi++) a[mi] = *(const short8*)(rA + mi * 16 * 64 + c);
#pragma unroll
      for (int nj = 0; nj < 4; nj++) b[nj] = *(const short8*)(rB + nj * 16 * 64 + c);
#pragma unroll
      for (int mi = 0; mi < 4; mi++)
#pragma unroll
        for (int nj = 0; nj < 4; nj++)
          acc[mi][nj] = mfma16(a[mi], b[nj], acc[mi][nj]);
    }
  }

#pragma unroll
  for (int mi = 0; mi < 4; mi++)
#pragma unroll
    for (int r = 0; r < 4; r++) {
      int rowl = wr * 64 + mi * 16 + qd * 4 + r;
      if (mt * 128 + rowl < count) {
        float* dst = y_sorted + (size_t)(hb + mt * 128 + rowl) * D_DIM
                   + nb * 128 + wc * 64 + l16;
#pragma unroll
        for (int nj = 0; nj < 4; nj++)
          dst[nj * 16] = acc[mi][nj][r];
      }
    }
}

// ---------------- combine: y[t] = ys[row(t,0)] + ys[row(t,1)] ------------------------
__global__ __launch_bounds__(256) void combine_kernel(
    const float* __restrict__ y_sorted, const int* __restrict__ tok2row,
    float* __restrict__ outY) {
  int t = blockIdx.x;
  int r0 = tok2row[t * 2], r1 = tok2row[t * 2 + 1];
  int i = threadIdx.x * 8;
  const floatx4* a = (const floatx4*)(y_sorted + (size_t)r0 * D_DIM + i);
  const floatx4* b = (const floatx4*)(y_sorted + (size_t)r1 * D_DIM + i);
  floatx4* o = (floatx4*)(outY + (size_t)t * D_DIM + i);
  o[0] = a[0] + b[0];
  o[1] = a[1] + b[1];
}

extern "C" void kernel_launch(void* const* d_in, const int* in_sizes, int n_in,
                              void* d_out, int out_size, void* d_ws, size_t ws_size,
                              hipStream_t stream) {
  (void)in_sizes; (void)n_in; (void)out_size; (void)ws_size;
  const float* hidden = (const float*)d_in[0];
  const float* gate_w = (const float*)d_in[1];
  const float* w_gate = (const float*)d_in[2];
  const float* w_up   = (const float*)d_in[3];
  const float* w_down = (const float*)d_in[4];
  float* out = (float*)d_out;
  float* outY = out;                                   // [T, D]
  float* outLogits = out + (size_t)T_TOK * D_DIM;      // [T, E]

  char* ws = (char*)d_ws;
  size_t off = 0;
  int* counts = (int*)(ws + off); off += 256;
  int* tok_ids = (int*)(ws + off); off += (size_t)N_EXP * T_TOK * 4;
  float* tok_wts = (float*)(ws + off); off += (size_t)N_EXP * T_TOK * 4;
  int* tok2row = (int*)(ws + off); off += (size_t)T_TOK * 2 * 4;
  short* x_bf = (short*)(ws + off); off += (size_t)T_TOK * D_DIM * 2;
  short* pwg = (short*)(ws + off); off += (size_t)N_EXP * F_DIM * D_DIM * 2;
  short* pwu = (short*)(ws + off); off += (size_t)N_EXP * F_DIM * D_DIM * 2;
  short* pwd = (short*)(ws + off); off += (size_t)N_EXP * D_DIM * F_DIM * 2;
  short* h_sorted = (short*)(ws + off); off += (size_t)T_TOK * 2 * F_DIM * 2;
  float* y_sorted = (float*)(ws + off); off += (size_t)T_TOK * 2 * D_DIM * 4;

  hipMemsetAsync(counts, 0, 256, stream);

  pack_wgwu<<<dim3(16, 32, N_EXP), 256, 0, stream>>>(w_gate, pwg);
  pack_wgwu<<<dim3(16, 32, N_EXP), 256, 0, stream>>>(w_up, pwu);
  pack_wd<<<dim3(16, 16, N_EXP), 256, 0, stream>>>(w_down, pwd);

  router_kernel<<<T_TOK, 256, 0, stream>>>(hidden, gate_w, x_bf, outLogits,
                                           counts, tok_ids, tok_wts);
  tok2row_kernel<<<1, 256, 0, stream>>>(counts, tok_ids, tok2row);

  gemm1_kernel<<<dim3(N_EXP * 16, F_DIM / 64), 256, 0, stream>>>(
      x_bf, pwg, pwu, counts, tok_ids, tok_wts, h_sorted);

  gemm2_kernel<<<dim3(N_EXP * 16, D_DIM / 128), 256, 0, stream>>>(
      h_sorted, pwd, counts, y_sorted);

  combine_kernel<<<T_TOK, 256, 0, stream>>>(y_sorted, tok2row, outY);
}